// Round 1
// baseline (1090.459 us; speedup 1.0000x reference)
//
#include <hip/hip_runtime.h>
#include <cstdint>
#include <cstddef>

namespace {
constexpr int kB = 2048;
constexpr int kN = 65536;
constexpr int kF = 128;
constexpr int kK = 3;
constexpr int kLabels = 10;
constexpr int kSlices = 4;
constexpr int kCps = kN / kSlices;      // 16384 cols per slice
constexpr int kRows = 16;               // query rows per workgroup
constexpr int kTpb = 256;
constexpr int kCc = 4;                  // columns per thread per tile
constexpr int kTileC = kTpb * kCc;      // 1024 cols per tile
constexpr int kTiles = kCps / kTileC;   // 16
constexpr int kIMax = 0x7fffffff;
}

// Insert candidate (dd, ii) into sorted top-3 (D0,I0)<=(D1,I1)<=(D2,I2)
// under lexicographic (distance, index) order — reproduces jax.lax.top_k's
// stable lowest-index-first tie-breaking on -distance.
#define TOP3_INSERT(dd, ii, D0, I0, D1, I1, D2, I2)                              \
  do {                                                                           \
    float _d = (dd); int _i = (ii);                                              \
    if (_d < (D0) || (_d == (D0) && _i < (I0))) {                                \
      (D2) = (D1); (I2) = (I1); (D1) = (D0); (I1) = (I0); (D0) = _d; (I0) = _i;  \
    } else if (_d < (D1) || (_d == (D1) && _i < (I1))) {                         \
      (D2) = (D1); (I2) = (I1); (D1) = _d; (I1) = _i;                            \
    } else if (_d < (D2) || (_d == (D2) && _i < (I2))) {                         \
      (D2) = _d; (I2) = _i;                                                      \
    }                                                                            \
  } while (0)

// left[i] = sum_f x[i][f]^2 ; right[j] = sum_f (features[f]*train[j][f])^2
// One wave (64 lanes) per row; lane reads float2 (coalesced 512B/row/wave).
__global__ __launch_bounds__(kTpb) void sumsq_kernel(
    const float* __restrict__ x, const float* __restrict__ train,
    const float* __restrict__ features, float* __restrict__ left,
    float* __restrict__ right) {
  const int wid = (int)((blockIdx.x * kTpb + threadIdx.x) >> 6);
  const int lane = threadIdx.x & 63;
  if (wid >= kB + kN) return;
  const float2 fv = reinterpret_cast<const float2*>(features)[lane];
  const float* src;
  float m0, m1;
  if (wid < kB) {
    src = x + (size_t)wid * kF;
    m0 = 1.0f; m1 = 1.0f;            // left uses raw x (no features)
  } else {
    src = train + (size_t)(wid - kB) * kF;
    m0 = fv.x; m1 = fv.y;            // right uses features*train
  }
  const float2 v = reinterpret_cast<const float2*>(src)[lane];
  const float a = v.x * m0, b = v.y * m1;
  float s = a * a + b * b;
  #pragma unroll
  for (int m = 1; m <= 32; m <<= 1) s += __shfl_xor(s, m);
  if (lane == 0) {
    if (wid < kB) left[wid] = s;
    else right[wid - kB] = s;
  }
}

// Fused distance + per-slice top-3.
// grid = (kB/kRows, kSlices). Per tile: compute 16x1024 distances into LDS,
// then wave-parallel top-3 scan (wave w owns rows 4w..4w+3).
__global__ __launch_bounds__(kTpb, 2) void dist_topk_kernel(
    const float* __restrict__ x, const float* __restrict__ train,
    const float* __restrict__ features, const float* __restrict__ left,
    const float* __restrict__ right, float* __restrict__ part_d,
    int* __restrict__ part_i) {
  __shared__ float Xs[kRows][kF];       // 8 KB, features folded in
  __shared__ float Ls[kRows];
  __shared__ float dbuf[kRows][kTileC]; // 64 KB distance tile
  __shared__ float run_d[kRows][kK];
  __shared__ int run_i[kRows][kK];

  const int rb = blockIdx.x;
  const int slice = blockIdx.y;
  const int row0 = rb * kRows;
  const int col0 = slice * kCps;
  const int t = threadIdx.x;

  // Stage X block with features folded: dot(x, f*w) == dot(f*x, w).
  for (int i = t; i < kRows * kF / 4; i += kTpb) {
    float4 xv = reinterpret_cast<const float4*>(x + (size_t)row0 * kF)[i];
    const float4 fv = reinterpret_cast<const float4*>(features)[i & (kF / 4 - 1)];
    xv.x *= fv.x; xv.y *= fv.y; xv.z *= fv.z; xv.w *= fv.w;
    reinterpret_cast<float4*>(&Xs[0][0])[i] = xv;
  }
  if (t < kRows) Ls[t] = left[row0 + t];
  if (t < kRows * kK) {
    run_d[t / kK][t % kK] = __builtin_inff();
    run_i[t / kK][t % kK] = kIMax;
  }
  __syncthreads();

  for (int tile = 0; tile < kTiles; ++tile) {
    const int cbase = col0 + tile * kTileC;
    const int j0 = cbase + t * kCc;   // this thread's 4 consecutive train rows

    float acc[kRows][kCc];
    #pragma unroll
    for (int r = 0; r < kRows; ++r) {
      #pragma unroll
      for (int c = 0; c < kCc; ++c) acc[r][c] = 0.0f;
    }

    const float4* wp = reinterpret_cast<const float4*>(train + (size_t)j0 * kF);
    #pragma unroll 2
    for (int kq = 0; kq < kF / 4; ++kq) {
      const float4 w0 = wp[0 * (kF / 4) + kq];
      const float4 w1 = wp[1 * (kF / 4) + kq];
      const float4 w2 = wp[2 * (kF / 4) + kq];
      const float4 w3 = wp[3 * (kF / 4) + kq];
      #pragma unroll
      for (int r = 0; r < kRows; ++r) {
        const float4 xv = reinterpret_cast<const float4*>(&Xs[r][0])[kq];
        acc[r][0] = fmaf(xv.w, w0.w, fmaf(xv.z, w0.z, fmaf(xv.y, w0.y, fmaf(xv.x, w0.x, acc[r][0]))));
        acc[r][1] = fmaf(xv.w, w1.w, fmaf(xv.z, w1.z, fmaf(xv.y, w1.y, fmaf(xv.x, w1.x, acc[r][1]))));
        acc[r][2] = fmaf(xv.w, w2.w, fmaf(xv.z, w2.z, fmaf(xv.y, w2.y, fmaf(xv.x, w2.x, acc[r][2]))));
        acc[r][3] = fmaf(xv.w, w3.w, fmaf(xv.z, w3.z, fmaf(xv.y, w3.y, fmaf(xv.x, w3.x, acc[r][3]))));
      }
    }

    const float4 rj = *reinterpret_cast<const float4*>(right + j0);
    #pragma unroll
    for (int r = 0; r < kRows; ++r) {
      const float l = Ls[r];
      float4 dv;
      dv.x = sqrtf(l + rj.x) - 2.0f * acc[r][0];
      dv.y = sqrtf(l + rj.y) - 2.0f * acc[r][1];
      dv.z = sqrtf(l + rj.z) - 2.0f * acc[r][2];
      dv.w = sqrtf(l + rj.w) - 2.0f * acc[r][3];
      *reinterpret_cast<float4*>(&dbuf[r][t * kCc]) = dv;
    }
    __syncthreads();

    // Phase 2: wave wv scans rows [wv*4, wv*4+4).
    {
      const int wv = t >> 6;
      const int lane = t & 63;
      #pragma unroll
      for (int rr = 0; rr < kRows / 4; ++rr) {
        const int r = wv * (kRows / 4) + rr;
        float d0 = __builtin_inff(), d1 = d0, d2 = d0;
        int i0 = kIMax, i1 = kIMax, i2 = kIMax;
        #pragma unroll
        for (int s = 0; s < kTileC / 64; ++s) {
          const int c = lane + s * 64;
          TOP3_INSERT(dbuf[r][c], cbase + c, d0, i0, d1, i1, d2, i2);
        }
        // 6-step butterfly merge across the wave (all lanes converge).
        #pragma unroll
        for (int m = 1; m <= 32; m <<= 1) {
          const float e0 = __shfl_xor(d0, m), e1 = __shfl_xor(d1, m), e2 = __shfl_xor(d2, m);
          const int f0 = __shfl_xor(i0, m), f1 = __shfl_xor(i1, m), f2 = __shfl_xor(i2, m);
          TOP3_INSERT(e0, f0, d0, i0, d1, i1, d2, i2);
          TOP3_INSERT(e1, f1, d0, i0, d1, i1, d2, i2);
          TOP3_INSERT(e2, f2, d0, i0, d1, i1, d2, i2);
        }
        if (lane == 0) {
          float g0 = run_d[r][0], g1 = run_d[r][1], g2 = run_d[r][2];
          int h0 = run_i[r][0], h1 = run_i[r][1], h2 = run_i[r][2];
          TOP3_INSERT(d0, i0, g0, h0, g1, h1, g2, h2);
          TOP3_INSERT(d1, i1, g0, h0, g1, h1, g2, h2);
          TOP3_INSERT(d2, i2, g0, h0, g1, h1, g2, h2);
          run_d[r][0] = g0; run_d[r][1] = g1; run_d[r][2] = g2;
          run_i[r][0] = h0; run_i[r][1] = h1; run_i[r][2] = h2;
        }
      }
    }
    __syncthreads();
  }

  if (t < kRows) {
    const int row = row0 + t;
    #pragma unroll
    for (int k = 0; k < kK; ++k) {
      part_d[((size_t)row * kSlices + slice) * kK + k] = run_d[t][k];
      part_i[((size_t)row * kSlices + slice) * kK + k] = run_i[t][k];
    }
  }
}

// Merge per-slice partials, gather labels, emit all four outputs (as f32).
__global__ __launch_bounds__(kTpb) void finalize_kernel(
    const float* __restrict__ part_d, const int* __restrict__ part_i,
    const int* __restrict__ labels, float* __restrict__ out) {
  const int b = blockIdx.x * kTpb + threadIdx.x;
  if (b >= kB) return;
  float d0 = __builtin_inff(), d1 = d0, d2 = d0;
  int i0 = kIMax, i1 = kIMax, i2 = kIMax;
  for (int s = 0; s < kSlices; ++s) {   // slices in increasing-j order (tie safety)
    #pragma unroll
    for (int k = 0; k < kK; ++k) {
      const float d = part_d[((size_t)b * kSlices + s) * kK + k];
      const int i = part_i[((size_t)b * kSlices + s) * kK + k];
      TOP3_INSERT(d, i, d0, i0, d1, i1, d2, i2);
    }
  }
  const int l0 = labels[i0], l1 = labels[i1], l2 = labels[i2];
  const int o = (l0 + l1 + l2) / kK;   // non-negative -> trunc == floor
  float* one_hot = out;                              // [B][10]
  float* values = out + (size_t)kB * kLabels;        // [B][3]
  float* indices = values + (size_t)kB * kK;         // [B][3]
  float* labs = indices + (size_t)kB * kK;           // [B][3]
  #pragma unroll
  for (int c = 0; c < kLabels; ++c)
    one_hot[(size_t)b * kLabels + c] = (c == o) ? 1.0f : 0.0f;
  values[b * kK + 0] = -d0; values[b * kK + 1] = -d1; values[b * kK + 2] = -d2;
  indices[b * kK + 0] = (float)i0; indices[b * kK + 1] = (float)i1; indices[b * kK + 2] = (float)i2;
  labs[b * kK + 0] = (float)l0; labs[b * kK + 1] = (float)l1; labs[b * kK + 2] = (float)l2;
}

extern "C" void kernel_launch(void* const* d_in, const int* in_sizes, int n_in,
                              void* d_out, int out_size, void* d_ws, size_t ws_size,
                              hipStream_t stream) {
  const float* x = (const float*)d_in[0];        // [B,F] f32
  const float* train = (const float*)d_in[1];    // [N,F] f32
  const int* labels = (const int*)d_in[2];       // [N] i32
  const float* features = (const float*)d_in[3]; // [F] f32
  float* out = (float*)d_out;

  // Workspace layout (all f32/i32, ~456 KB total).
  float* left = (float*)d_ws;                       // [B]
  float* right = left + kB;                         // [N]
  float* part_d = right + kN;                       // [B][kSlices][kK]
  int* part_i = (int*)(part_d + (size_t)kB * kSlices * kK);

  const int waves = kB + kN;
  const int blocks1 = (waves * 64 + kTpb - 1) / kTpb;
  sumsq_kernel<<<blocks1, kTpb, 0, stream>>>(x, train, features, left, right);

  dim3 grid2(kB / kRows, kSlices);
  dist_topk_kernel<<<grid2, kTpb, 0, stream>>>(x, train, features, left, right,
                                               part_d, part_i);

  finalize_kernel<<<(kB + kTpb - 1) / kTpb, kTpb, 0, stream>>>(part_d, part_i,
                                                               labels, out);
}

// Round 2
// 385.697 us; speedup vs baseline: 2.8272x; 2.8272x over previous
//
#include <hip/hip_runtime.h>
#include <hip/hip_bf16.h>
#include <cstdint>
#include <cstddef>

typedef short bf16x8 __attribute__((ext_vector_type(8)));
typedef float f32x4 __attribute__((ext_vector_type(4)));

namespace {
constexpr int kB = 2048;
constexpr int kN = 65536;
constexpr int kF = 128;
constexpr int kLabels = 10;
constexpr int kIMax = 0x7fffffff;

// main-kernel geometry
constexpr int BM = 256;             // rows per WG
constexpr int BN = 256;             // cols per n-tile
constexpr int SLICE = 2048;         // cols per WG
constexpr int NTILES = SLICE / BN;  // 8
constexpr int NCH = 12;             // K chunks: 384/32 (3 bf16 passes of 128)
constexpr int NSUB = kN / 32;       // 2048 subtiles of 32 cols
constexpr float kMargin = 0.05f;    // >> 2*(bf16x3 dot error ~1e-3)
}

// Lexicographic (distance, index) top-3 insert — matches jax.lax.top_k ties.
#define TOP3_INSERT(dd, ii, D0, I0, D1, I1, D2, I2)                              \
  do {                                                                           \
    float _d = (dd); int _i = (ii);                                              \
    if (_d < (D0) || (_d == (D0) && _i < (I0))) {                                \
      (D2) = (D1); (I2) = (I1); (D1) = (D0); (I1) = (I0); (D0) = _d; (I0) = _i;  \
    } else if (_d < (D1) || (_d == (D1) && _i < (I1))) {                         \
      (D2) = (D1); (I2) = (I1); (D1) = _d; (I1) = _i;                            \
    } else if (_d < (D2) || (_d == (D2) && _i < (I2))) {                         \
      (D2) = _d; (I2) = _i;                                                      \
    }                                                                            \
  } while (0)

__device__ inline unsigned short f2bf(float a) {
  __hip_bfloat16 h = __float2bfloat16(a);
  return __builtin_bit_cast(unsigned short, h);
}

__device__ inline void gload_lds16(const void* g, void* l) {
  __builtin_amdgcn_global_load_lds(
      (const __attribute__((address_space(1))) void*)g,
      (__attribute__((address_space(3))) void*)l, 16, 0, 0);
}

// ---------------- kernel 1a: pack bf16 hi/lo splits ----------------
// Ap[row][0:128]=bf16(f*x) hi, [128:256]=lo.  Bp[col][0:128]=bf16(w) hi, [128:256]=lo.
__global__ __launch_bounds__(256) void pack_kernel(
    const float* __restrict__ x, const float* __restrict__ train,
    const float* __restrict__ features, unsigned short* __restrict__ Ap,
    unsigned short* __restrict__ Bp) {
  const int id = blockIdx.x * 256 + threadIdx.x;
  if (id >= (kB + kN) * 32) return;
  const int ent = id >> 5, q = id & 31;
  float4 v;
  unsigned short* dst;
  if (ent < kB) {
    v = reinterpret_cast<const float4*>(x)[(size_t)ent * 32 + q];
    const float4 f = reinterpret_cast<const float4*>(features)[q];
    v.x *= f.x; v.y *= f.y; v.z *= f.z; v.w *= f.w;
    dst = Ap + (size_t)ent * 256;
  } else {
    v = reinterpret_cast<const float4*>(train)[(size_t)(ent - kB) * 32 + q];
    dst = Bp + (size_t)(ent - kB) * 256;
  }
  ushort4 hi, lo;
  {
    unsigned short h;
    h = f2bf(v.x); hi.x = h; lo.x = f2bf(v.x - __bfloat162float(__builtin_bit_cast(__hip_bfloat16, h)));
    h = f2bf(v.y); hi.y = h; lo.y = f2bf(v.y - __bfloat162float(__builtin_bit_cast(__hip_bfloat16, h)));
    h = f2bf(v.z); hi.z = h; lo.z = f2bf(v.z - __bfloat162float(__builtin_bit_cast(__hip_bfloat16, h)));
    h = f2bf(v.w); hi.w = h; lo.w = f2bf(v.w - __bfloat162float(__builtin_bit_cast(__hip_bfloat16, h)));
  }
  *reinterpret_cast<ushort4*>(dst + q * 4) = hi;
  *reinterpret_cast<ushort4*>(dst + 128 + q * 4) = lo;
}

// ---------------- kernel 1b: sumsq (round-1 verbatim, matched reference) ---
__global__ __launch_bounds__(256) void sumsq_kernel(
    const float* __restrict__ x, const float* __restrict__ train,
    const float* __restrict__ features, float* __restrict__ left,
    float* __restrict__ right) {
  const int wid = (int)((blockIdx.x * 256 + threadIdx.x) >> 6);
  const int lane = threadIdx.x & 63;
  if (wid >= kB + kN) return;
  const float2 fv = reinterpret_cast<const float2*>(features)[lane];
  const float* src;
  float m0, m1;
  if (wid < kB) {
    src = x + (size_t)wid * kF;
    m0 = 1.0f; m1 = 1.0f;
  } else {
    src = train + (size_t)(wid - kB) * kF;
    m0 = fv.x; m1 = fv.y;
  }
  const float2 v = reinterpret_cast<const float2*>(src)[lane];
  const float a = v.x * m0, b = v.y * m1;
  float s = a * a + b * b;
  #pragma unroll
  for (int m = 1; m <= 32; m <<= 1) s += __shfl_xor(s, m);
  if (lane == 0) {
    if (wid < kB) left[wid] = s;
    else right[wid - kB] = s;
  }
}

// ---------------- kernel 2: bf16x3 MFMA distance + per-subtile min ---------
// grid (32 slices, 8 m-blocks), 512 threads (8 waves: 4m x 2n over 256x256 tile)
__global__ __launch_bounds__(512, 2) void knn_main_kernel(
    const unsigned short* __restrict__ Ap, const unsigned short* __restrict__ Bp,
    const float* __restrict__ left, const float* __restrict__ right,
    float* __restrict__ minbuf) {
  __shared__ alignas(16) unsigned short lsA[2][BM * 32];  // 16 KB x2
  __shared__ alignas(16) unsigned short lsB[2][BN * 32];  // 16 KB x2
  __shared__ alignas(16) float lsR[SLICE];                // 8 KB

  const int slice = blockIdx.x;
  const int mb = blockIdx.y;
  const int row0 = mb * BM;
  const int col0 = slice * SLICE;
  const int t = threadIdx.x;
  const int lane = t & 63;
  const int wm = (t >> 6) >> 1;  // 0..3
  const int wn = (t >> 6) & 1;   // 0..1

  // stage right-slice (2048 f32) into LDS
  reinterpret_cast<float4*>(lsR)[t] =
      reinterpret_cast<const float4*>(right + col0)[t];

  // left per lane-row (16 rows per lane)
  float lrow[4][4];
  #pragma unroll
  for (int mf = 0; mf < 4; ++mf)
    #pragma unroll
    for (int rg = 0; rg < 4; ++rg)
      lrow[mf][rg] = left[row0 + wm * 64 + mf * 16 + (lane >> 4) * 4 + rg];

  // staging addresses: instr i covers rows i*128 + t/4, 16B slot p = t&3.
  // LDS linear [row][4 slots]; source slot XOR-swizzled so that swizzled
  // frag reads (below) see data slot s at phys s ^ ((row>>1)&3).
  const int rA = t >> 2;
  const int p = t & 3;
  size_t gbaseA[2], gbaseB[2];
  int ldsoff[2];
  #pragma unroll
  for (int i = 0; i < 2; ++i) {
    const int r = i * 128 + rA;
    const int ps = p ^ ((r >> 1) & 3);
    gbaseA[i] = (size_t)(row0 + r) * 512 + (size_t)ps * 16;
    gbaseB[i] = (size_t)(col0 + r) * 512 + (size_t)ps * 16;
    ldsoff[i] = i * 8192 + t * 16;
  }

  // fragment LDS byte offsets (swizzled reads)
  int offA[4], offB[8];
  #pragma unroll
  for (int mf = 0; mf < 4; ++mf) {
    const int rl = wm * 64 + mf * 16 + (lane & 15);
    offA[mf] = rl * 64 + (((lane >> 4) ^ ((rl >> 1) & 3)) * 16);
  }
  #pragma unroll
  for (int nf = 0; nf < 8; ++nf) {
    const int cl = wn * 128 + nf * 16 + (lane & 15);
    offB[nf] = cl * 64 + (((lane >> 4) ^ ((cl >> 1) & 3)) * 16);
  }

  const char* ApB = (const char*)Ap;
  const char* BpB = (const char*)Bp;

  auto stage = [&](int buf, int c, int nt) {
    // chunk->packed-k maps: A = [xh|xl|xh], B = [wh|wh|wl]
    const int skA = (c < 4) ? c * 32 : ((c < 8) ? 128 + (c - 4) * 32 : (c - 8) * 32);
    const int skB = (c < 4) ? c * 32 : ((c < 8) ? (c - 4) * 32 : 128 + (c - 8) * 32);
    char* lA = (char*)&lsA[buf][0];
    char* lB = (char*)&lsB[buf][0];
    #pragma unroll
    for (int i = 0; i < 2; ++i) {
      gload_lds16(ApB + gbaseA[i] + (size_t)skA * 2, lA + ldsoff[i]);
      gload_lds16(BpB + gbaseB[i] + (size_t)nt * 131072 + (size_t)skB * 2, lB + ldsoff[i]);
    }
  };

  const bool writer = ((lane >> 2) & 3) == (lane >> 4);

  for (int nt = 0; nt < NTILES; ++nt) {
    f32x4 acc[4][8];
    #pragma unroll
    for (int mf = 0; mf < 4; ++mf)
      #pragma unroll
      for (int nf = 0; nf < 8; ++nf)
        acc[mf][nf] = (f32x4){0.f, 0.f, 0.f, 0.f};

    int buf = 0;
    stage(0, 0, nt);
    __syncthreads();
    for (int c = 0; c < NCH; ++c) {
      if (c < NCH - 1) stage(buf ^ 1, c + 1, nt);
      const char* lA = (const char*)&lsA[buf][0];
      const char* lB = (const char*)&lsB[buf][0];
      bf16x8 a[4], b[8];
      #pragma unroll
      for (int mf = 0; mf < 4; ++mf)
        a[mf] = *reinterpret_cast<const bf16x8*>(lA + offA[mf]);
      #pragma unroll
      for (int nf = 0; nf < 8; ++nf)
        b[nf] = *reinterpret_cast<const bf16x8*>(lB + offB[nf]);
      #pragma unroll
      for (int mf = 0; mf < 4; ++mf)
        #pragma unroll
        for (int nf = 0; nf < 8; ++nf)
          acc[mf][nf] = __builtin_amdgcn_mfma_f32_16x16x32_bf16(
              a[mf], b[nf], acc[mf][nf], 0, 0, 0);
      __syncthreads();
      buf ^= 1;
    }

    // epilogue: distance + per-(row, 32-col-subtile) min
    float rj[8];
    #pragma unroll
    for (int nf = 0; nf < 8; ++nf)
      rj[nf] = lsR[nt * 256 + wn * 128 + nf * 16 + (lane & 15)];
    const int subbase = slice * 64 + nt * 8 + wn * 4;
    #pragma unroll
    for (int mf = 0; mf < 4; ++mf) {
      #pragma unroll
      for (int rg = 0; rg < 4; ++rg) {
        const float l = lrow[mf][rg];
        float m0, m1, m2, m3;
        #pragma unroll
        for (int nfp = 0; nfp < 4; ++nfp) {
          float da = sqrtf(l + rj[2 * nfp]) - 2.0f * acc[mf][2 * nfp][rg];
          float db = sqrtf(l + rj[2 * nfp + 1]) - 2.0f * acc[mf][2 * nfp + 1][rg];
          float mm = fminf(da, db);
          mm = fminf(mm, __shfl_xor(mm, 1));
          mm = fminf(mm, __shfl_xor(mm, 2));
          mm = fminf(mm, __shfl_xor(mm, 4));
          mm = fminf(mm, __shfl_xor(mm, 8));
          if (nfp == 0) m0 = mm; else if (nfp == 1) m1 = mm;
          else if (nfp == 2) m2 = mm; else m3 = mm;
        }
        if (writer) {
          const int row = row0 + wm * 64 + mf * 16 + (lane >> 4) * 4 + rg;
          const int nfp = lane & 3;
          const float vv = (nfp == 0) ? m0 : (nfp == 1) ? m1 : (nfp == 2) ? m2 : m3;
          minbuf[(size_t)row * NSUB + subbase + nfp] = vv;
        }
      }
    }
    __syncthreads();
  }
}

// ---------------- kernel 3: select subtiles, exact fp32 rescore, outputs ---
__global__ __launch_bounds__(256) void select_rescore_kernel(
    const float* __restrict__ x, const float* __restrict__ train,
    const float* __restrict__ features, const float* __restrict__ left,
    const float* __restrict__ right, const int* __restrict__ labels,
    const float* __restrict__ minbuf, float* __restrict__ out) {
  __shared__ float Xs[4][kF];
  const int t = threadIdx.x;
  if (t < 128) {
    const int rr = t >> 5, q = t & 31;
    float4 xv = reinterpret_cast<const float4*>(
        x + (size_t)(blockIdx.x * 4 + rr) * kF)[q];
    const float4 f = reinterpret_cast<const float4*>(features)[q];
    xv.x *= f.x; xv.y *= f.y; xv.z *= f.z; xv.w *= f.w;
    reinterpret_cast<float4*>(&Xs[rr][0])[q] = xv;
  }
  __syncthreads();
  const int wave = t >> 6, lane = t & 63;
  const int row = blockIdx.x * 4 + wave;
  const float lr = left[row];
  const float* mrow = minbuf + (size_t)row * NSUB;

  // pass 1: 3rd-smallest subtile min
  float v0 = __builtin_inff(), v1 = v0, v2 = v0;
  #pragma unroll 4
  for (int i = 0; i < NSUB / 64; ++i) {
    const float m = mrow[i * 64 + lane];
    if (m < v0) { v2 = v1; v1 = v0; v0 = m; }
    else if (m < v1) { v2 = v1; v1 = m; }
    else if (m < v2) { v2 = m; }
  }
  #pragma unroll
  for (int msk = 1; msk <= 32; msk <<= 1) {
    const float e0 = __shfl_xor(v0, msk), e1 = __shfl_xor(v1, msk), e2 = __shfl_xor(v2, msk);
    if (e0 < v0) { v2 = v1; v1 = v0; v0 = e0; } else if (e0 < v1) { v2 = v1; v1 = e0; } else if (e0 < v2) v2 = e0;
    if (e1 < v0) { v2 = v1; v1 = v0; v0 = e1; } else if (e1 < v1) { v2 = v1; v1 = e1; } else if (e1 < v2) v2 = e1;
    if (e2 < v0) { v2 = v1; v1 = v0; v0 = e2; } else if (e2 < v1) { v2 = v1; v1 = e2; } else if (e2 < v2) v2 = e2;
  }
  const float tau = v2 + kMargin;

  // pass 2: exact rescore of selected subtiles (round-1 fmaf chain, bit-exact)
  float d0 = __builtin_inff(), d1 = d0, d2 = d0;
  int i0 = kIMax, i1 = kIMax, i2 = kIMax;
  for (int base = 0; base < NSUB; base += 64) {
    const float m = mrow[base + lane];
    unsigned long long msk = __ballot(m <= tau);
    while (msk) {
      const int bpos = __builtin_ctzll(msk);
      msk &= msk - 1;
      const int sub = base + bpos;
      if (lane < 32) {
        const int j = sub * 32 + lane;
        const float4* wp = reinterpret_cast<const float4*>(train + (size_t)j * kF);
        float acc = 0.f;
        #pragma unroll 8
        for (int kq = 0; kq < 32; ++kq) {
          const float4 w4 = wp[kq];
          const float4 x4 = reinterpret_cast<const float4*>(&Xs[wave][0])[kq];
          acc = fmaf(x4.w, w4.w, fmaf(x4.z, w4.z, fmaf(x4.y, w4.y, fmaf(x4.x, w4.x, acc))));
        }
        const float d = sqrtf(lr + right[j]) - 2.0f * acc;
        TOP3_INSERT(d, j, d0, i0, d1, i1, d2, i2);
      }
    }
  }
  #pragma unroll
  for (int msk = 1; msk <= 32; msk <<= 1) {
    const float e0 = __shfl_xor(d0, msk), e1 = __shfl_xor(d1, msk), e2 = __shfl_xor(d2, msk);
    const int f0 = __shfl_xor(i0, msk), f1 = __shfl_xor(i1, msk), f2 = __shfl_xor(i2, msk);
    TOP3_INSERT(e0, f0, d0, i0, d1, i1, d2, i2);
    TOP3_INSERT(e1, f1, d0, i0, d1, i1, d2, i2);
    TOP3_INSERT(e2, f2, d0, i0, d1, i1, d2, i2);
  }
  if (lane == 0) {
    const int l0 = labels[i0], l1 = labels[i1], l2 = labels[i2];
    const int o = (l0 + l1 + l2) / 3;
    float* one_hot = out;
    float* values = out + (size_t)kB * kLabels;
    float* indices = values + (size_t)kB * 3;
    float* labs = indices + (size_t)kB * 3;
    #pragma unroll
    for (int c = 0; c < kLabels; ++c)
      one_hot[(size_t)row * kLabels + c] = (c == o) ? 1.0f : 0.0f;
    values[row * 3 + 0] = -d0; values[row * 3 + 1] = -d1; values[row * 3 + 2] = -d2;
    indices[row * 3 + 0] = (float)i0; indices[row * 3 + 1] = (float)i1; indices[row * 3 + 2] = (float)i2;
    labs[row * 3 + 0] = (float)l0; labs[row * 3 + 1] = (float)l1; labs[row * 3 + 2] = (float)l2;
  }
}

extern "C" void kernel_launch(void* const* d_in, const int* in_sizes, int n_in,
                              void* d_out, int out_size, void* d_ws, size_t ws_size,
                              hipStream_t stream) {
  const float* x = (const float*)d_in[0];
  const float* train = (const float*)d_in[1];
  const int* labels = (const int*)d_in[2];
  const float* features = (const float*)d_in[3];
  float* out = (float*)d_out;

  char* ws = (char*)d_ws;
  unsigned short* Bp = (unsigned short*)ws;                       // 32 MB
  unsigned short* Ap = (unsigned short*)(ws + 33554432);          // 1 MB
  float* left = (float*)(ws + 34603008);                          // 8 KB
  float* right = (float*)(ws + 34611200);                         // 256 KB
  float* minbuf = (float*)(ws + 34873344);                        // 16 MB

  pack_kernel<<<((kB + kN) * 32 + 255) / 256, 256, 0, stream>>>(
      x, train, features, Ap, Bp);
  sumsq_kernel<<<((kB + kN) * 64 + 255) / 256, 256, 0, stream>>>(
      x, train, features, left, right);
  knn_main_kernel<<<dim3(32, 8), 512, 0, stream>>>(Ap, Bp, left, right, minbuf);
  select_rescore_kernel<<<kB / 4, 256, 0, stream>>>(
      x, train, features, left, right, labels, minbuf, out);
}

// Round 4
// 337.650 us; speedup vs baseline: 3.2296x; 1.1423x over previous
//
#include <hip/hip_runtime.h>
#include <hip/hip_bf16.h>
#include <cstdint>
#include <cstddef>

typedef short bf16x8 __attribute__((ext_vector_type(8)));
typedef float f32x4 __attribute__((ext_vector_type(4)));

namespace {
constexpr int kB = 2048;
constexpr int kN = 65536;
constexpr int kF = 128;
constexpr int kLabels = 10;
constexpr int kIMax = 0x7fffffff;

constexpr int BM = 256;             // rows per WG
constexpr int BN = 256;             // cols per n-tile
constexpr int SLICE = 2048;         // cols per WG
constexpr int NTILES = SLICE / BN;  // 8
constexpr int NCH = 12;             // K chunks: 384/32 (3 bf16 passes of 128)
constexpr int NCHT = NTILES * NCH;  // 96 chunks total per WG
constexpr int NSUB = kN / 32;       // 2048 subtiles of 32 cols
constexpr float kMargin = 0.05f;    // >> 2*(bf16x3 dot error ~2e-3)
}

#define TOP3_INSERT(dd, ii, D0, I0, D1, I1, D2, I2)                              \
  do {                                                                           \
    float _d = (dd); int _i = (ii);                                              \
    if (_d < (D0) || (_d == (D0) && _i < (I0))) {                                \
      (D2) = (D1); (I2) = (I1); (D1) = (D0); (I1) = (I0); (D0) = _d; (I0) = _i;  \
    } else if (_d < (D1) || (_d == (D1) && _i < (I1))) {                         \
      (D2) = (D1); (I2) = (I1); (D1) = _d; (I1) = _i;                            \
    } else if (_d < (D2) || (_d == (D2) && _i < (I2))) {                         \
      (D2) = _d; (I2) = _i;                                                      \
    }                                                                            \
  } while (0)

__device__ inline unsigned short f2bf(float a) {
  __hip_bfloat16 h = __float2bfloat16(a);
  return __builtin_bit_cast(unsigned short, h);
}
__device__ inline float bf2f(unsigned short u) {
  return __bfloat162float(__builtin_bit_cast(__hip_bfloat16, u));
}

__device__ inline void gload_lds16(const void* g, void* l) {
  __builtin_amdgcn_global_load_lds(
      (const __attribute__((address_space(1))) void*)g,
      (__attribute__((address_space(3))) void*)l, 16, 0, 0);
}

// ---------- kernel 1: fused pack (bf16 hi/lo) + sumsq ----------
// One wave per entry (row of x or train). Lane covers 2 consecutive floats.
// A pack = bf16split(f*x), left = sum x^2 ; B pack = bf16split(w), right = sum (f*w)^2.
__global__ __launch_bounds__(256) void pack_sumsq_kernel(
    const float* __restrict__ x, const float* __restrict__ train,
    const float* __restrict__ features, unsigned short* __restrict__ Ap,
    unsigned short* __restrict__ Bp, float* __restrict__ left,
    float* __restrict__ right) {
  const int wid = (int)((blockIdx.x * 256 + threadIdx.x) >> 6);
  const int lane = threadIdx.x & 63;
  if (wid >= kB + kN) return;
  const float2 fv = reinterpret_cast<const float2*>(features)[lane];
  const float* src;
  unsigned short* dst;
  float pm0, pm1, sm0, sm1;
  if (wid < kB) {
    src = x + (size_t)wid * kF;
    dst = Ap + (size_t)wid * 256;
    pm0 = fv.x; pm1 = fv.y;   // pack f*x
    sm0 = 1.0f; sm1 = 1.0f;   // left = sum x^2
  } else {
    src = train + (size_t)(wid - kB) * kF;
    dst = Bp + (size_t)(wid - kB) * 256;
    pm0 = 1.0f; pm1 = 1.0f;   // pack raw w
    sm0 = fv.x; sm1 = fv.y;   // right = sum (f*w)^2
  }
  const float2 v = reinterpret_cast<const float2*>(src)[lane];
  const float pa = v.x * pm0, pb = v.y * pm1;
  const float sa = v.x * sm0, sb = v.y * sm1;
  // hi/lo bf16 split
  const unsigned short ha = f2bf(pa), hb = f2bf(pb);
  const unsigned short la = f2bf(pa - bf2f(ha)), lb = f2bf(pb - bf2f(hb));
  reinterpret_cast<unsigned int*>(dst)[lane] = (unsigned int)ha | ((unsigned int)hb << 16);
  reinterpret_cast<unsigned int*>(dst + 128)[lane] = (unsigned int)la | ((unsigned int)lb << 16);
  float s = sa * sa + sb * sb;
  #pragma unroll
  for (int m = 1; m <= 32; m <<= 1) s += __shfl_xor(s, m);
  if (lane == 0) {
    if (wid < kB) left[wid] = s;
    else right[wid - kB] = s;
  }
}

// ---------- kernel 2: bf16x3 MFMA distance + per-subtile min ----------
// grid (32 slices, 8 m-blocks), 512 threads (8 waves: 4m x 2n over 256x256).
// 4-deep LDS pipeline, counted vmcnt — never drains in the main loop.
__global__ __launch_bounds__(512, 2) void knn_main_kernel(
    const unsigned short* __restrict__ Ap, const unsigned short* __restrict__ Bp,
    const float* __restrict__ left, const float* __restrict__ right,
    float* __restrict__ minbuf) {
  __shared__ alignas(16) unsigned short lsA[4][BM * 32];  // 16 KB x4
  __shared__ alignas(16) unsigned short lsB[4][BN * 32];  // 16 KB x4
  __shared__ alignas(16) float lsR[SLICE];                // 8 KB

  const int slice = blockIdx.x;
  const int mb = blockIdx.y;
  const int row0 = mb * BM;
  const int col0 = slice * SLICE;
  const int t = threadIdx.x;
  const int lane = t & 63;
  const int wm = (t >> 6) >> 1;  // 0..3
  const int wn = (t >> 6) & 1;   // 0..1

  // stage right-slice (2048 f32) into LDS
  reinterpret_cast<float4*>(lsR)[t] =
      reinterpret_cast<const float4*>(right + col0)[t];

  // left per lane-row (16 rows per lane)
  float lrow[4][4];
  #pragma unroll
  for (int mf = 0; mf < 4; ++mf)
    #pragma unroll
    for (int rg = 0; rg < 4; ++rg)
      lrow[mf][rg] = left[row0 + wm * 64 + mf * 16 + (lane >> 4) * 4 + rg];

  // staging addresses (verbatim round-2, verified): instr i covers rows
  // i*128 + t/4, slot p = t&3; source slot XOR-swizzled, LDS linear.
  const int rA = t >> 2;
  const int p = t & 3;
  size_t gbaseA[2], gbaseB[2];
  int ldsoff[2];
  #pragma unroll
  for (int i = 0; i < 2; ++i) {
    const int r = i * 128 + rA;
    const int ps = p ^ ((r >> 1) & 3);
    gbaseA[i] = (size_t)(row0 + r) * 512 + (size_t)ps * 16;
    gbaseB[i] = (size_t)(col0 + r) * 512 + (size_t)ps * 16;
    ldsoff[i] = i * 8192 + t * 16;
  }

  // fragment LDS byte offsets (swizzled reads)
  int offA[4], offB[8];
  #pragma unroll
  for (int mf = 0; mf < 4; ++mf) {
    const int rl = wm * 64 + mf * 16 + (lane & 15);
    offA[mf] = rl * 64 + (((lane >> 4) ^ ((rl >> 1) & 3)) * 16);
  }
  #pragma unroll
  for (int nf = 0; nf < 8; ++nf) {
    const int cl = wn * 128 + nf * 16 + (lane & 15);
    offB[nf] = cl * 64 + (((lane >> 4) ^ ((cl >> 1) & 3)) * 16);
  }

  const char* ApB = (const char*)Ap;
  const char* BpB = (const char*)Bp;

  auto stage = [&](int buf, int c, int nt) {
    // chunk->packed-k maps: A = [xh|xl|xh], B = [wh|wh|wl]
    const int skA = (c < 4) ? c * 32 : ((c < 8) ? 128 + (c - 4) * 32 : (c - 8) * 32);
    const int skB = (c < 4) ? c * 32 : ((c < 8) ? (c - 4) * 32 : 128 + (c - 8) * 32);
    char* lA = (char*)&lsA[buf][0];
    char* lB = (char*)&lsB[buf][0];
    #pragma unroll
    for (int i = 0; i < 2; ++i) {
      gload_lds16(ApB + gbaseA[i] + (size_t)skA * 2, lA + ldsoff[i]);
      gload_lds16(BpB + gbaseB[i] + (size_t)nt * 131072 + (size_t)skB * 2, lB + ldsoff[i]);
    }
  };

  const bool writer = ((lane >> 2) & 3) == (lane >> 4);

  // Drain everything once, sync (protects lsR init), then start the pipeline.
  asm volatile("s_waitcnt vmcnt(0) lgkmcnt(0)" ::: "memory");
  __syncthreads();

  // prologue: prefetch chunks 0,1,2
  int pn = 0, pc = 0;  // next chunk to stage (nt, c)
  #pragma unroll
  for (int i = 0; i < 3; ++i) {
    stage(i, pc, pn);
    if (++pc == NCH) { pc = 0; ++pn; }
  }

  int g = 0;  // global chunk index
  for (int nt = 0; nt < NTILES; ++nt) {
    f32x4 acc[4][8];
    #pragma unroll
    for (int mf = 0; mf < 4; ++mf)
      #pragma unroll
      for (int nf = 0; nf < 8; ++nf)
        acc[mf][nf] = (f32x4){0.f, 0.f, 0.f, 0.f};

    for (int c = 0; c < NCH; ++c, ++g) {
      if (g + 3 < NCHT) {
        stage((g + 3) & 3, pc, pn);
        if (++pc == NCH) { pc = 0; ++pn; }
      }
      // counted wait: stage(g) complete iff <= 3 newer stages outstanding.
      {
        const int rem = NCHT - 1 - g;  // stages issued after g
        if (rem >= 3)      asm volatile("s_waitcnt vmcnt(12)" ::: "memory");
        else if (rem == 2) asm volatile("s_waitcnt vmcnt(8)" ::: "memory");
        else if (rem == 1) asm volatile("s_waitcnt vmcnt(4)" ::: "memory");
        else               asm volatile("s_waitcnt vmcnt(0)" ::: "memory");
      }
      __builtin_amdgcn_s_barrier();
      asm volatile("" ::: "memory");

      const char* lA = (const char*)&lsA[g & 3][0];
      const char* lB = (const char*)&lsB[g & 3][0];
      bf16x8 a[4], b[8];
      #pragma unroll
      for (int mf = 0; mf < 4; ++mf)
        a[mf] = *reinterpret_cast<const bf16x8*>(lA + offA[mf]);
      #pragma unroll
      for (int nf = 0; nf < 8; ++nf)
        b[nf] = *reinterpret_cast<const bf16x8*>(lB + offB[nf]);
      asm volatile("s_waitcnt lgkmcnt(0)" ::: "memory");
      __builtin_amdgcn_sched_barrier(0);
      __builtin_amdgcn_s_setprio(1);
      #pragma unroll
      for (int mf = 0; mf < 4; ++mf)
        #pragma unroll
        for (int nf = 0; nf < 8; ++nf)
          acc[mf][nf] = __builtin_amdgcn_mfma_f32_16x16x32_bf16(
              a[mf], b[nf], acc[mf][nf], 0, 0, 0);
      __builtin_amdgcn_s_setprio(0);
      __builtin_amdgcn_s_barrier();   // reads of buf g done before its reuse
      asm volatile("" ::: "memory");
    }

    // epilogue (regs + lsR + global only — no LDS writes, no barrier needed)
    float rj[8];
    #pragma unroll
    for (int nf = 0; nf < 8; ++nf)
      rj[nf] = lsR[nt * 256 + wn * 128 + nf * 16 + (lane & 15)];
    const int subbase = slice * 64 + nt * 8 + wn * 4;
    #pragma unroll
    for (int mf = 0; mf < 4; ++mf) {
      #pragma unroll
      for (int rg = 0; rg < 4; ++rg) {
        const float l = lrow[mf][rg];
        float m0, m1, m2, m3;
        #pragma unroll
        for (int nfp = 0; nfp < 4; ++nfp) {
          float da = sqrtf(l + rj[2 * nfp]) - 2.0f * acc[mf][2 * nfp][rg];
          float db = sqrtf(l + rj[2 * nfp + 1]) - 2.0f * acc[mf][2 * nfp + 1][rg];
          float mm = fminf(da, db);
          mm = fminf(mm, __shfl_xor(mm, 1));
          mm = fminf(mm, __shfl_xor(mm, 2));
          mm = fminf(mm, __shfl_xor(mm, 4));
          mm = fminf(mm, __shfl_xor(mm, 8));
          if (nfp == 0) m0 = mm; else if (nfp == 1) m1 = mm;
          else if (nfp == 2) m2 = mm; else m3 = mm;
        }
        if (writer) {
          const int row = row0 + wm * 64 + mf * 16 + (lane >> 4) * 4 + rg;
          const int nfp = lane & 3;
          const float vv = (nfp == 0) ? m0 : (nfp == 1) ? m1 : (nfp == 2) ? m2 : m3;
          minbuf[(size_t)row * NSUB + subbase + nfp] = vv;
        }
      }
    }
  }
}

// ---------- kernel 3: select subtiles, exact fp32 rescore, outputs ----------
__global__ __launch_bounds__(256) void select_rescore_kernel(
    const float* __restrict__ x, const float* __restrict__ train,
    const float* __restrict__ features, const float* __restrict__ left,
    const float* __restrict__ right, const int* __restrict__ labels,
    const float* __restrict__ minbuf, float* __restrict__ out) {
  __shared__ float Xs[4][kF];
  const int t = threadIdx.x;
  if (t < 128) {
    const int rr = t >> 5, q = t & 31;
    float4 xv = reinterpret_cast<const float4*>(
        x + (size_t)(blockIdx.x * 4 + rr) * kF)[q];
    const float4 f = reinterpret_cast<const float4*>(features)[q];
    xv.x *= f.x; xv.y *= f.y; xv.z *= f.z; xv.w *= f.w;
    reinterpret_cast<float4*>(&Xs[rr][0])[q] = xv;
  }
  __syncthreads();
  const int wave = t >> 6, lane = t & 63;
  const int row = blockIdx.x * 4 + wave;
  const float lr = left[row];
  const float* mrow = minbuf + (size_t)row * NSUB;

  // pass 1: 3rd-smallest subtile min
  float v0 = __builtin_inff(), v1 = v0, v2 = v0;
  #pragma unroll 4
  for (int i = 0; i < NSUB / 64; ++i) {
    const float m = mrow[i * 64 + lane];
    if (m < v0) { v2 = v1; v1 = v0; v0 = m; }
    else if (m < v1) { v2 = v1; v1 = m; }
    else if (m < v2) { v2 = m; }
  }
  #pragma unroll
  for (int msk = 1; msk <= 32; msk <<= 1) {
    const float e0 = __shfl_xor(v0, msk), e1 = __shfl_xor(v1, msk), e2 = __shfl_xor(v2, msk);
    if (e0 < v0) { v2 = v1; v1 = v0; v0 = e0; } else if (e0 < v1) { v2 = v1; v1 = e0; } else if (e0 < v2) v2 = e0;
    if (e1 < v0) { v2 = v1; v1 = v0; v0 = e1; } else if (e1 < v1) { v2 = v1; v1 = e1; } else if (e1 < v2) v2 = e1;
    if (e2 < v0) { v2 = v1; v1 = v0; v0 = e2; } else if (e2 < v1) { v2 = v1; v1 = e2; } else if (e2 < v2) v2 = e2;
  }
  const float tau = v2 + kMargin;

  // pass 2: exact fp32 rescore of selected subtiles
  float d0 = __builtin_inff(), d1 = d0, d2 = d0;
  int i0 = kIMax, i1 = kIMax, i2 = kIMax;
  for (int base = 0; base < NSUB; base += 64) {
    const float m = mrow[base + lane];
    unsigned long long msk = __ballot(m <= tau);
    while (msk) {
      const int bpos = __builtin_ctzll(msk);
      msk &= msk - 1;
      const int sub = base + bpos;
      if (lane < 32) {
        const int j = sub * 32 + lane;
        const float4* wp = reinterpret_cast<const float4*>(train + (size_t)j * kF);
        float acc = 0.f;
        #pragma unroll 8
        for (int kq = 0; kq < 32; ++kq) {
          const float4 w4 = wp[kq];
          const float4 x4 = reinterpret_cast<const float4*>(&Xs[wave][0])[kq];
          acc = fmaf(x4.w, w4.w, fmaf(x4.z, w4.z, fmaf(x4.y, w4.y, fmaf(x4.x, w4.x, acc))));
        }
        const float d = sqrtf(lr + right[j]) - 2.0f * acc;
        TOP3_INSERT(d, j, d0, i0, d1, i1, d2, i2);
      }
    }
  }
  #pragma unroll
  for (int msk = 1; msk <= 32; msk <<= 1) {
    const float e0 = __shfl_xor(d0, msk), e1 = __shfl_xor(d1, msk), e2 = __shfl_xor(d2, msk);
    const int f0 = __shfl_xor(i0, msk), f1 = __shfl_xor(i1, msk), f2 = __shfl_xor(i2, msk);
    TOP3_INSERT(e0, f0, d0, i0, d1, i1, d2, i2);
    TOP3_INSERT(e1, f1, d0, i0, d1, i1, d2, i2);
    TOP3_INSERT(e2, f2, d0, i0, d1, i1, d2, i2);
  }
  if (lane == 0) {
    const int l0 = labels[i0], l1 = labels[i1], l2 = labels[i2];
    const int o = (l0 + l1 + l2) / 3;
    float* one_hot = out;
    float* values = out + (size_t)kB * kLabels;
    float* indices = values + (size_t)kB * 3;
    float* labs = indices + (size_t)kB * 3;
    #pragma unroll
    for (int c = 0; c < kLabels; ++c)
      one_hot[(size_t)row * kLabels + c] = (c == o) ? 1.0f : 0.0f;
    values[row * 3 + 0] = -d0; values[row * 3 + 1] = -d1; values[row * 3 + 2] = -d2;
    indices[row * 3 + 0] = (float)i0; indices[row * 3 + 1] = (float)i1; indices[row * 3 + 2] = (float)i2;
    labs[row * 3 + 0] = (float)l0; labs[row * 3 + 1] = (float)l1; labs[row * 3 + 2] = (float)l2;
  }
}

extern "C" void kernel_launch(void* const* d_in, const int* in_sizes, int n_in,
                              void* d_out, int out_size, void* d_ws, size_t ws_size,
                              hipStream_t stream) {
  const float* x = (const float*)d_in[0];
  const float* train = (const float*)d_in[1];
  const int* labels = (const int*)d_in[2];
  const float* features = (const float*)d_in[3];
  float* out = (float*)d_out;

  char* ws = (char*)d_ws;
  unsigned short* Bp = (unsigned short*)ws;                       // 32 MB
  unsigned short* Ap = (unsigned short*)(ws + 33554432);          // 1 MB
  float* left = (float*)(ws + 34603008);                          // 8 KB
  float* right = (float*)(ws + 34611200);                         // 256 KB
  float* minbuf = (float*)(ws + 34873344);                        // 16 MB

  pack_sumsq_kernel<<<((kB + kN) * 64 + 255) / 256, 256, 0, stream>>>(
      x, train, features, Ap, Bp, left, right);
  knn_main_kernel<<<dim3(32, 8), 512, 0, stream>>>(Ap, Bp, left, right, minbuf);
  select_rescore_kernel<<<kB / 4, 256, 0, stream>>>(
      x, train, features, left, right, labels, minbuf, out);
}

// Round 5
// 299.173 us; speedup vs baseline: 3.6449x; 1.1286x over previous
//
#include <hip/hip_runtime.h>
#include <hip/hip_bf16.h>
#include <cstdint>
#include <cstddef>

typedef short bf16x8 __attribute__((ext_vector_type(8)));
typedef float f32x4 __attribute__((ext_vector_type(4)));

namespace {
constexpr int kB = 2048;
constexpr int kN = 65536;
constexpr int kF = 128;
constexpr int kLabels = 10;
constexpr int kIMax = 0x7fffffff;

constexpr int BM = 256;             // rows per WG
constexpr int BN = 256;             // cols per n-tile
constexpr int SLICE = 2048;         // cols per WG
constexpr int NTILES = SLICE / BN;  // 8
constexpr int NCH = 12;             // K chunks: 384/32 (3 bf16 passes of 128)
constexpr int NCHT = NTILES * NCH;  // 96 chunks total per WG
constexpr int NSUB = kN / 32;       // 2048 bins of 32 (strided) cols
constexpr float kMargin = 0.05f;    // >> 2*(bf16x3 dot error ~2e-3)
}

#define TOP3_INSERT(dd, ii, D0, I0, D1, I1, D2, I2)                              \
  do {                                                                           \
    float _d = (dd); int _i = (ii);                                              \
    if (_d < (D0) || (_d == (D0) && _i < (I0))) {                                \
      (D2) = (D1); (I2) = (I1); (D1) = (D0); (I1) = (I0); (D0) = _d; (I0) = _i;  \
    } else if (_d < (D1) || (_d == (D1) && _i < (I1))) {                         \
      (D2) = (D1); (I2) = (I1); (D1) = _d; (I1) = _i;                            \
    } else if (_d < (D2) || (_d == (D2) && _i < (I2))) {                         \
      (D2) = _d; (I2) = _i;                                                      \
    }                                                                            \
  } while (0)

__device__ inline unsigned short f2bf(float a) {
  __hip_bfloat16 h = __float2bfloat16(a);
  return __builtin_bit_cast(unsigned short, h);
}
__device__ inline float bf2f(unsigned short u) {
  return __bfloat162float(__builtin_bit_cast(__hip_bfloat16, u));
}

__device__ inline void gload_lds16(const void* g, void* l) {
  __builtin_amdgcn_global_load_lds(
      (const __attribute__((address_space(1))) void*)g,
      (__attribute__((address_space(3))) void*)l, 16, 0, 0);
}

// ---------- kernel 1: fused pack (bf16 hi/lo) + sumsq ----------
__global__ __launch_bounds__(256) void pack_sumsq_kernel(
    const float* __restrict__ x, const float* __restrict__ train,
    const float* __restrict__ features, unsigned short* __restrict__ Ap,
    unsigned short* __restrict__ Bp, float* __restrict__ left,
    float* __restrict__ right) {
  const int wid = (int)((blockIdx.x * 256 + threadIdx.x) >> 6);
  const int lane = threadIdx.x & 63;
  if (wid >= kB + kN) return;
  const float2 fv = reinterpret_cast<const float2*>(features)[lane];
  const float* src;
  unsigned short* dst;
  float pm0, pm1, sm0, sm1;
  if (wid < kB) {
    src = x + (size_t)wid * kF;
    dst = Ap + (size_t)wid * 256;
    pm0 = fv.x; pm1 = fv.y;   // pack f*x
    sm0 = 1.0f; sm1 = 1.0f;   // left = sum x^2
  } else {
    src = train + (size_t)(wid - kB) * kF;
    dst = Bp + (size_t)(wid - kB) * 256;
    pm0 = 1.0f; pm1 = 1.0f;   // pack raw w
    sm0 = fv.x; sm1 = fv.y;   // right = sum (f*w)^2
  }
  const float2 v = reinterpret_cast<const float2*>(src)[lane];
  const float pa = v.x * pm0, pb = v.y * pm1;
  const float sa = v.x * sm0, sb = v.y * sm1;
  const unsigned short ha = f2bf(pa), hb = f2bf(pb);
  const unsigned short la = f2bf(pa - bf2f(ha)), lb = f2bf(pb - bf2f(hb));
  reinterpret_cast<unsigned int*>(dst)[lane] = (unsigned int)ha | ((unsigned int)hb << 16);
  reinterpret_cast<unsigned int*>(dst + 128)[lane] = (unsigned int)la | ((unsigned int)lb << 16);
  float s = sa * sa + sb * sb;
  #pragma unroll
  for (int m = 1; m <= 32; m <<= 1) s += __shfl_xor(s, m);
  if (lane == 0) {
    if (wid < kB) left[wid] = s;
    else right[wid - kB] = s;
  }
}

// ---------- kernel 2: bf16x3 MFMA distance + per-bin min ----------
// grid (32 slices, 8 m-blocks), 512 threads (8 waves: 4m x 2n over 256x256).
// 4-deep LDS pipeline, counted vmcnt (never drains in-loop), compiler-scheduled
// ds_read<->MFMA interleave (no lgkmcnt(0)/sched_barrier pin).
__global__ __launch_bounds__(512, 2) void knn_main_kernel(
    const unsigned short* __restrict__ Ap, const unsigned short* __restrict__ Bp,
    const float* __restrict__ left, const float* __restrict__ right,
    float* __restrict__ minbuf) {
  __shared__ alignas(16) unsigned short lsA[4][BM * 32];  // 16 KB x4
  __shared__ alignas(16) unsigned short lsB[4][BN * 32];  // 16 KB x4
  __shared__ alignas(16) float lsR[SLICE];                // 8 KB

  const int slice = blockIdx.x;
  const int mb = blockIdx.y;
  const int row0 = mb * BM;
  const int col0 = slice * SLICE;
  const int t = threadIdx.x;
  const int lane = t & 63;
  const int wm = (t >> 6) >> 1;  // 0..3
  const int wn = (t >> 6) & 1;   // 0..1

  // stage right-slice (2048 f32) into LDS
  reinterpret_cast<float4*>(lsR)[t] =
      reinterpret_cast<const float4*>(right + col0)[t];

  // left per lane-row (16 rows per lane)
  float lrow[4][4];
  #pragma unroll
  for (int mf = 0; mf < 4; ++mf)
    #pragma unroll
    for (int rg = 0; rg < 4; ++rg)
      lrow[mf][rg] = left[row0 + wm * 64 + mf * 16 + (lane >> 4) * 4 + rg];

  // staging addresses (verified round-2): instr i covers rows i*128 + t/4,
  // slot p = t&3; source slot XOR-swizzled, LDS linear.
  const int rA = t >> 2;
  const int p = t & 3;
  size_t gbaseA[2], gbaseB[2];
  int ldsoff[2];
  #pragma unroll
  for (int i = 0; i < 2; ++i) {
    const int r = i * 128 + rA;
    const int ps = p ^ ((r >> 1) & 3);
    gbaseA[i] = (size_t)(row0 + r) * 512 + (size_t)ps * 16;
    gbaseB[i] = (size_t)(col0 + r) * 512 + (size_t)ps * 16;
    ldsoff[i] = i * 8192 + t * 16;
  }

  // fragment LDS byte offsets (swizzled reads)
  int offA[4], offB[8];
  #pragma unroll
  for (int mf = 0; mf < 4; ++mf) {
    const int rl = wm * 64 + mf * 16 + (lane & 15);
    offA[mf] = rl * 64 + (((lane >> 4) ^ ((rl >> 1) & 3)) * 16);
  }
  #pragma unroll
  for (int nf = 0; nf < 8; ++nf) {
    const int cl = wn * 128 + nf * 16 + (lane & 15);
    offB[nf] = cl * 64 + (((lane >> 4) ^ ((cl >> 1) & 3)) * 16);
  }

  const char* ApB = (const char*)Ap;
  const char* BpB = (const char*)Bp;

  auto stage = [&](int buf, int c, int nt) {
    // chunk->packed-k maps: A = [xh|xl|xh], B = [wh|wh|wl]
    const int skA = (c < 4) ? c * 32 : ((c < 8) ? 128 + (c - 4) * 32 : (c - 8) * 32);
    const int skB = (c < 4) ? c * 32 : ((c < 8) ? (c - 4) * 32 : 128 + (c - 8) * 32);
    char* lA = (char*)&lsA[buf][0];
    char* lB = (char*)&lsB[buf][0];
    #pragma unroll
    for (int i = 0; i < 2; ++i) {
      gload_lds16(ApB + gbaseA[i] + (size_t)skA * 2, lA + ldsoff[i]);
      gload_lds16(BpB + gbaseB[i] + (size_t)nt * 131072 + (size_t)skB * 2, lB + ldsoff[i]);
    }
  };

  // Drain everything once, sync (protects lsR init), then start the pipeline.
  asm volatile("s_waitcnt vmcnt(0) lgkmcnt(0)" ::: "memory");
  __syncthreads();

  // prologue: prefetch chunks 0,1,2
  int pn = 0, pc = 0;  // next chunk to stage (nt, c)
  #pragma unroll
  for (int i = 0; i < 3; ++i) {
    stage(i, pc, pn);
    if (++pc == NCH) { pc = 0; ++pn; }
  }

  // bin geometry: bin collects cols {nf*16 + bq*4 + g}; reduction = per-lane
  // fmin over nf, then xor-1/xor-2 across the 4-lane group. bq = (lane>>2)&3.
  const bool bwriter = (lane & 3) == 0;

  int g = 0;  // global chunk index
  for (int nt = 0; nt < NTILES; ++nt) {
    f32x4 acc[4][8];
    #pragma unroll
    for (int mf = 0; mf < 4; ++mf)
      #pragma unroll
      for (int nf = 0; nf < 8; ++nf)
        acc[mf][nf] = (f32x4){0.f, 0.f, 0.f, 0.f};

    for (int c = 0; c < NCH; ++c, ++g) {
      if (g + 3 < NCHT) {
        stage((g + 3) & 3, pc, pn);
        if (++pc == NCH) { pc = 0; ++pn; }
      }
      // counted wait: stage(g) complete iff <= 3 newer stages outstanding.
      {
        const int rem = NCHT - 1 - g;  // stages issued after g
        if (rem >= 3)      asm volatile("s_waitcnt vmcnt(12)" ::: "memory");
        else if (rem == 2) asm volatile("s_waitcnt vmcnt(8)" ::: "memory");
        else if (rem == 1) asm volatile("s_waitcnt vmcnt(4)" ::: "memory");
        else               asm volatile("s_waitcnt vmcnt(0)" ::: "memory");
      }
      __builtin_amdgcn_s_barrier();
      asm volatile("" ::: "memory");

      const char* lA = (const char*)&lsA[g & 3][0];
      const char* lB = (const char*)&lsB[g & 3][0];
      bf16x8 a[4], b[8];
      #pragma unroll
      for (int mf = 0; mf < 4; ++mf)
        a[mf] = *reinterpret_cast<const bf16x8*>(lA + offA[mf]);
      #pragma unroll
      for (int nf = 0; nf < 8; ++nf)
        b[nf] = *reinterpret_cast<const bf16x8*>(lB + offB[nf]);
      // NO lgkmcnt(0)/sched_barrier pin: compiler emits fine-grained lgkmcnt
      // and interleaves ds_read with MFMA (m97/m141 evidence). All reads are
      // consumed by MFMAs below, so they complete before barrier-2.
      __builtin_amdgcn_s_setprio(1);
      #pragma unroll
      for (int mf = 0; mf < 4; ++mf)
        #pragma unroll
        for (int nf = 0; nf < 8; ++nf)
          acc[mf][nf] = __builtin_amdgcn_mfma_f32_16x16x32_bf16(
              a[mf], b[nf], acc[mf][nf], 0, 0, 0);
      __builtin_amdgcn_s_setprio(0);
      asm volatile("" ::: "memory");
      __builtin_amdgcn_s_barrier();   // reads of buf g done before its reuse
      asm volatile("" ::: "memory");
    }

    // epilogue: distance + per-bin (32 strided cols) min.
    // Per (mf,rg): 8 distances -> per-lane fmin tree over nf (7 fmin) ->
    // xor-1/xor-2 butterfly (2 shfl) -> writer lane stores. 32 shfl/thread/nt.
    float rj[8];
    #pragma unroll
    for (int nf = 0; nf < 8; ++nf)
      rj[nf] = lsR[nt * 256 + wn * 128 + nf * 16 + (lane & 15)];
    const int binbase = slice * 64 + nt * 8 + wn * 4 + ((lane >> 2) & 3);
    #pragma unroll
    for (int mf = 0; mf < 4; ++mf) {
      #pragma unroll
      for (int rg = 0; rg < 4; ++rg) {
        const float l = lrow[mf][rg];
        float d[8];
        #pragma unroll
        for (int nf = 0; nf < 8; ++nf)
          d[nf] = sqrtf(l + rj[nf]) - 2.0f * acc[mf][nf][rg];
        d[0] = fminf(d[0], d[4]); d[1] = fminf(d[1], d[5]);
        d[2] = fminf(d[2], d[6]); d[3] = fminf(d[3], d[7]);
        d[0] = fminf(d[0], d[2]); d[1] = fminf(d[1], d[3]);
        float v = fminf(d[0], d[1]);
        v = fminf(v, __shfl_xor(v, 1));
        v = fminf(v, __shfl_xor(v, 2));
        if (bwriter) {
          const int row = row0 + wm * 64 + mf * 16 + (lane >> 4) * 4 + rg;
          minbuf[(size_t)row * NSUB + binbase] = v;
        }
      }
    }
  }
}

// ---------- kernel 3: select bins, exact fp32 rescore, outputs ----------
__global__ __launch_bounds__(256) void select_rescore_kernel(
    const float* __restrict__ x, const float* __restrict__ train,
    const float* __restrict__ features, const float* __restrict__ left,
    const float* __restrict__ right, const int* __restrict__ labels,
    const float* __restrict__ minbuf, float* __restrict__ out) {
  __shared__ float Xs[4][kF];
  const int t = threadIdx.x;
  if (t < 128) {
    const int rr = t >> 5, q = t & 31;
    float4 xv = reinterpret_cast<const float4*>(
        x + (size_t)(blockIdx.x * 4 + rr) * kF)[q];
    const float4 f = reinterpret_cast<const float4*>(features)[q];
    xv.x *= f.x; xv.y *= f.y; xv.z *= f.z; xv.w *= f.w;
    reinterpret_cast<float4*>(&Xs[rr][0])[q] = xv;
  }
  __syncthreads();
  const int wave = t >> 6, lane = t & 63;
  const int row = blockIdx.x * 4 + wave;
  const float lr = left[row];
  const float* mrow = minbuf + (size_t)row * NSUB;

  // pass 1: 3rd-smallest bin min
  float v0 = __builtin_inff(), v1 = v0, v2 = v0;
  #pragma unroll 4
  for (int i = 0; i < NSUB / 64; ++i) {
    const float m = mrow[i * 64 + lane];
    if (m < v0) { v2 = v1; v1 = v0; v0 = m; }
    else if (m < v1) { v2 = v1; v1 = m; }
    else if (m < v2) { v2 = m; }
  }
  #pragma unroll
  for (int msk = 1; msk <= 32; msk <<= 1) {
    const float e0 = __shfl_xor(v0, msk), e1 = __shfl_xor(v1, msk), e2 = __shfl_xor(v2, msk);
    if (e0 < v0) { v2 = v1; v1 = v0; v0 = e0; } else if (e0 < v1) { v2 = v1; v1 = e0; } else if (e0 < v2) v2 = e0;
    if (e1 < v0) { v2 = v1; v1 = v0; v0 = e1; } else if (e1 < v1) { v2 = v1; v1 = e1; } else if (e1 < v2) v2 = e1;
    if (e2 < v0) { v2 = v1; v1 = v0; v0 = e2; } else if (e2 < v1) { v2 = v1; v1 = e2; } else if (e2 < v2) v2 = e2;
  }
  const float tau = v2 + kMargin;

  // pass 2: exact fp32 rescore of selected bins.
  // bin sub -> cols { (sub>>2)*128 + nf*16 + (sub&3)*4 + g : nf 0..7, g 0..3 }
  float d0 = __builtin_inff(), d1 = d0, d2 = d0;
  int i0 = kIMax, i1 = kIMax, i2 = kIMax;
  for (int base = 0; base < NSUB; base += 64) {
    const float m = mrow[base + lane];
    unsigned long long msk = __ballot(m <= tau);
    while (msk) {
      const int bpos = __builtin_ctzll(msk);
      msk &= msk - 1;
      const int sub = base + bpos;
      if (lane < 32) {
        const int j = (sub >> 2) * 128 + (lane >> 2) * 16 + (sub & 3) * 4 + (lane & 3);
        const float4* wp = reinterpret_cast<const float4*>(train + (size_t)j * kF);
        float acc = 0.f;
        #pragma unroll 8
        for (int kq = 0; kq < 32; ++kq) {
          const float4 w4 = wp[kq];
          const float4 x4 = reinterpret_cast<const float4*>(&Xs[wave][0])[kq];
          acc = fmaf(x4.w, w4.w, fmaf(x4.z, w4.z, fmaf(x4.y, w4.y, fmaf(x4.x, w4.x, acc))));
        }
        const float d = sqrtf(lr + right[j]) - 2.0f * acc;
        TOP3_INSERT(d, j, d0, i0, d1, i1, d2, i2);
      }
    }
  }
  #pragma unroll
  for (int msk = 1; msk <= 32; msk <<= 1) {
    const float e0 = __shfl_xor(d0, msk), e1 = __shfl_xor(d1, msk), e2 = __shfl_xor(d2, msk);
    const int f0 = __shfl_xor(i0, msk), f1 = __shfl_xor(i1, msk), f2 = __shfl_xor(i2, msk);
    TOP3_INSERT(e0, f0, d0, i0, d1, i1, d2, i2);
    TOP3_INSERT(e1, f1, d0, i0, d1, i1, d2, i2);
    TOP3_INSERT(e2, f2, d0, i0, d1, i1, d2, i2);
  }
  if (lane == 0) {
    const int l0 = labels[i0], l1 = labels[i1], l2 = labels[i2];
    const int o = (l0 + l1 + l2) / 3;
    float* one_hot = out;
    float* values = out + (size_t)kB * kLabels;
    float* indices = values + (size_t)kB * 3;
    float* labs = indices + (size_t)kB * 3;
    #pragma unroll
    for (int c = 0; c < kLabels; ++c)
      one_hot[(size_t)row * kLabels + c] = (c == o) ? 1.0f : 0.0f;
    values[row * 3 + 0] = -d0; values[row * 3 + 1] = -d1; values[row * 3 + 2] = -d2;
    indices[row * 3 + 0] = (float)i0; indices[row * 3 + 1] = (float)i1; indices[row * 3 + 2] = (float)i2;
    labs[row * 3 + 0] = (float)l0; labs[row * 3 + 1] = (float)l1; labs[row * 3 + 2] = (float)l2;
  }
}

extern "C" void kernel_launch(void* const* d_in, const int* in_sizes, int n_in,
                              void* d_out, int out_size, void* d_ws, size_t ws_size,
                              hipStream_t stream) {
  const float* x = (const float*)d_in[0];
  const float* train = (const float*)d_in[1];
  const int* labels = (const int*)d_in[2];
  const float* features = (const float*)d_in[3];
  float* out = (float*)d_out;

  char* ws = (char*)d_ws;
  unsigned short* Bp = (unsigned short*)ws;                       // 32 MB
  unsigned short* Ap = (unsigned short*)(ws + 33554432);          // 1 MB
  float* left = (float*)(ws + 34603008);                          // 8 KB
  float* right = (float*)(ws + 34611200);                         // 256 KB
  float* minbuf = (float*)(ws + 34873344);                        // 16 MB

  pack_sumsq_kernel<<<((kB + kN) * 64 + 255) / 256, 256, 0, stream>>>(
      x, train, features, Ap, Bp, left, right);
  knn_main_kernel<<<dim3(32, 8), 512, 0, stream>>>(Ap, Bp, left, right, minbuf);
  select_rescore_kernel<<<kB / 4, 256, 0, stream>>>(
      x, train, features, left, right, labels, minbuf, out);
}